// Round 5
// baseline (108.602 us; speedup 1.0000x reference)
//
#include <hip/hip_runtime.h>

// Row-wise top-K(32) of relu(A), zero elsewhere. N=8192 fp32 per row.
// One 256-thread block per row. TWO row touches only:
//   touch 1: histogram values > 2.0 (bits>>20 bins, monotonic for positive
//            floats) AND collect all (val,col) > 2.0 into an LDS list (~186).
//   touch 2: re-read row (L2-hot) and emit with the closed-form keep rule.
// Cutoff bin B found by wave-parallel suffix scans; its members are ballot-
// compacted from the candidate list (no atomics, no extra barrier) and the
// exact (value desc, col asc) rank-R boundary (vR,cR) computed in-register.
// Exact block-uniform fallback (full 2048-bin histogram) covers rows with
// < K values > 2.0 or candidate overflow.
//
// R1/R3 lesson: the compiler re-loads const __restrict__ data rather than
// holding 32 VGPRs of row data — so make the 2-touch structure explicit and
// keep VGPR low for occupancy. nt stores: keep (no harm); they did NOT
// improve L3 residency of A (FETCH pinned at ~134 MB across replays).

constexpr int N     = 8192;
constexpr int K     = 32;
constexpr int NBINS = 2048;      // positive fp32: bits>>20 in [0, 2048)
constexpr int SPEC_BASE = 1024;  // bin(2.0) = 1024; values > 2.0 -> [1024,2048)
constexpr int CAP   = 512;       // candidate list capacity (expected ~186)
constexpr int SLOTS = CAP / 64;
constexpr int BB    = 128;       // compacted cutoff-bin entries (expected ~26)
constexpr int BLOCK = 256;
constexpr float TSPEC = 2.0f;

typedef float f4 __attribute__((ext_vector_type(4)));

// Find cutoff bin B (the bin containing the K-th largest) and G = count
// strictly above B, from hist[base .. base+64*PER). All waves redundant.
template<int PER>
__device__ __forceinline__ bool find_cutoff(const unsigned* hist, int lane,
                                            int base, int& B, int& G) {
    unsigned s = 0;
    #pragma unroll
    for (int i = 0; i < PER; ++i)
        s += hist[base + lane * PER + ((i + lane) & (PER - 1))];  // staggered
    unsigned acc = s;                       // inclusive suffix sum over lanes
    #pragma unroll
    for (int off = 1; off < 64; off <<= 1) {
        unsigned t = __shfl_down(acc, off, 64);
        if (lane + off < 64) acc += t;
    }
    unsigned long long m = __ballot(acc >= (unsigned)K);
    if (m == 0ull) return false;
    int g = 63 - __clzll((long long)m);     // highest group with suffix >= K
    unsigned above = (g < 63) ? (unsigned)__shfl((int)acc, g + 1, 64) : 0u;
    unsigned h  = (lane < PER) ? hist[base + g * PER + lane] : 0u;
    unsigned a2 = h;                        // within-group suffix
    #pragma unroll
    for (int off = 1; off < 64; off <<= 1) {
        unsigned t = __shfl_down(a2, off, 64);
        if (lane + off < 64) a2 += t;
    }
    unsigned long long m2 = __ballot(above + a2 >= (unsigned)K);
    int bl = 63 - __clzll((long long)m2);
    B = base + g * PER + bl;
    G = (int)(above + (unsigned)__shfl((int)a2, bl, 64)
                    - (unsigned)__shfl((int)h,  bl, 64));
    return true;
}

__global__ __launch_bounds__(BLOCK)
void topk_relu_kernel(const float* __restrict__ A, float* __restrict__ Out) {
    const int row  = blockIdx.x;
    const int tid  = threadIdx.x;
    const int lane = tid & 63;

    __shared__ unsigned hist[NBINS];
    __shared__ float    cv[CAP];
    __shared__ int      cc[CAP];
    __shared__ float    bbv[BB];
    __shared__ int      bbc[BB];
    __shared__ unsigned ccnt;

    // zero only the speculative bins [1024, 2048)
    #pragma unroll
    for (int i = 0; i < (NBINS - SPEC_BASE) / BLOCK; ++i)
        hist[SPEC_BASE + tid + i * BLOCK] = 0u;
    if (tid == 0) ccnt = 0u;
    __syncthreads();

    // ---- touch 1: histogram + candidate-collect values > TSPEC ----
    const f4* __restrict__ Arow = reinterpret_cast<const f4*>(A + (size_t)row * N);
    #pragma unroll
    for (int i = 0; i < 8; ++i) {
        f4 v = Arow[i * BLOCK + tid];
        #pragma unroll
        for (int c = 0; c < 4; ++c) {
            float f = v[c];
            if (f > TSPEC) {
                atomicAdd(&hist[__float_as_uint(f) >> 20], 1u);
                unsigned ix = atomicAdd(&ccnt, 1u);
                if (ix < CAP) { cv[ix] = f; cc[ix] = (i * BLOCK + tid) * 4 + c; }
            }
        }
    }
    __syncthreads();

    // ---- cutoff bin (all waves redundant) ----
    int B, G;
    bool ok = find_cutoff<16>(hist, lane, SPEC_BASE, B, G);
    unsigned Call = ccnt;                   // block-uniform
    if (!ok || Call > (unsigned)CAP) {
        // exact fallback: full histogram of all positives + direct bin collect.
        // (Block-uniform branch; ~never taken for this distribution.)
        __syncthreads();                    // scan reads done before re-zero
        #pragma unroll
        for (int i = 0; i < NBINS / BLOCK; ++i) hist[tid + i * BLOCK] = 0u;
        if (tid == 0) ccnt = 0u;
        __syncthreads();
        #pragma unroll
        for (int i = 0; i < 8; ++i) {
            f4 v = Arow[i * BLOCK + tid];
            #pragma unroll
            for (int c = 0; c < 4; ++c) {
                float f = v[c];
                if (f > 0.0f) atomicAdd(&hist[__float_as_uint(f) >> 20], 1u);
            }
        }
        __syncthreads();
        if (!find_cutoff<32>(hist, lane, 0, B, G)) { B = -1; G = 0; }
        if (B >= 0) {
            #pragma unroll
            for (int i = 0; i < 8; ++i) {
                f4 v = Arow[i * BLOCK + tid];
                #pragma unroll
                for (int c = 0; c < 4; ++c) {
                    float f = v[c];
                    if (f > 0.0f && (int)(__float_as_uint(f) >> 20) == B) {
                        unsigned ix = atomicAdd(&ccnt, 1u);
                        if (ix < CAP) { cv[ix] = f; cc[ix] = (i * BLOCK + tid) * 4 + c; }
                    }
                }
            }
        }
        __syncthreads();
        Call = ccnt;
    }
    const int R = K - G;                    // boundary rank within bin B (>=1)

    // ---- rank-R boundary (vR, cR) of bin B; keep: f>vR || (f==vR && col<=cR)
    float vR = 0.0f;                        // B == -1: keep all positives
    int   cR = -1;
    if (B >= 0) {
        const int C = (int)min(Call, (unsigned)CAP);
        // ballot-compact bin-B entries into bbv/bbc. Every wave writes the
        // SAME values to the same slots (duplicate-identical writes: benign,
        // no barrier needed; each wave reads its own writes in order).
        int total = 0;
        #pragma unroll
        for (int s = 0; s < SLOTS; ++s) {
            const int j = lane + s * 64;
            bool flag = false; float fv = 0.0f; int fc = 0;
            if (j < C) {
                fv = cv[j];
                if ((int)(__float_as_uint(fv) >> 20) == B) { flag = true; fc = cc[j]; }
            }
            unsigned long long m = __ballot(flag);
            if (flag) {
                int pos = total + __popcll(m & ((1ull << lane) - 1ull));
                if (pos < BB) { bbv[pos] = fv; bbc[pos] = fc; }
            }
            total += (int)__popcll(m);
        }
        const int T = min(total, BB);       // expected ~26; guaranteed >= R
        float mv0 = -1.0f, mv1 = -1.0f; int mc0 = 0x7fffffff, mc1 = 0x7fffffff;
        if (lane      < T) { mv0 = bbv[lane];      mc0 = bbc[lane]; }
        if (lane + 64 < T) { mv1 = bbv[lane + 64]; mc1 = bbc[lane + 64]; }
        int r0 = 0, r1 = 0;
        for (int j = 0; j < T; ++j) {       // LDS broadcast reads
            const float vj = bbv[j];
            const int   cj = bbc[j];
            if (vj > mv0 || (vj == mv0 && cj < mc0)) r0++;
            if (vj > mv1 || (vj == mv1 && cj < mc1)) r1++;
        }
        float bv = 0.0f; int bc = -1; bool found = false;
        if (lane      < T && r0 == R - 1) { bv = mv0; bc = mc0; found = true; }
        if (lane + 64 < T && r1 == R - 1) { bv = mv1; bc = mc1; found = true; }
        vR = __int_as_float(0x7f800000);    // sentinel (boundary always found)
        unsigned long long bm = __ballot(found);
        if (bm != 0ull) {
            int src = (int)__ffsll((long long)bm) - 1;
            vR = __shfl(bv, src, 64);
            cR = __shfl(bc, src, 64);
        }
    }

    // ---- touch 2: re-read row (L2-hot) and emit one nt coalesced burst ----
    float* __restrict__ Orow = Out + (size_t)row * N;
    #pragma unroll
    for (int i = 0; i < 8; ++i) {
        f4 v = Arow[i * BLOCK + tid];
        f4 w;
        #pragma unroll
        for (int c = 0; c < 4; ++c) {
            float f   = v[c];
            int   col = (i * BLOCK + tid) * 4 + c;
            w[c] = ((f > vR) || (f == vR && col <= cR)) ? f : 0.0f;
        }
        __builtin_nontemporal_store(w, reinterpret_cast<f4*>(Orow) + i * BLOCK + tid);
    }
}

extern "C" void kernel_launch(void* const* d_in, const int* in_sizes, int n_in,
                              void* d_out, int out_size, void* d_ws, size_t ws_size,
                              hipStream_t stream) {
    const float* A   = (const float*)d_in[0];
    float*       Out = (float*)d_out;
    (void)in_sizes; (void)n_in; (void)d_ws; (void)ws_size; (void)out_size;
    topk_relu_kernel<<<dim3(N), dim3(BLOCK), 0, stream>>>(A, Out);
}

// Round 6
// 104.661 us; speedup vs baseline: 1.0376x; 1.0376x over previous
//
#include <hip/hip_runtime.h>

// Row-wise top-K(32) of relu(A), zero elsewhere. N=8192 fp32 per row.
// One 256-thread block per row. A is touched from global EXACTLY ONCE
// (R4 lesson: a second read stream of the 268 MB A through the 256 MB L3
// destroys cross-replay residency — FETCH went 134->255 MB, +16 us).
//
// touch 1: histogram values > 2.0 (bits>>20 bins, monotonic for positive
//          floats) AND collect all (val,col) > 2.0 into LDS (~186 entries).
// output:  dense nt ZERO burst (needs no A data; drain overlaps ranking),
//          then wave 0 scatters the <=32 selected (col,val) pairs from the
//          LDS candidate list — every kept value is > vR >= 2.0, so the
//          candidate list contains the whole selected set.
// Exact block-uniform fallback (full 2048-bin histogram + dense emit,
// re-reading the L2-hot row) covers rows with < K values > 2.0.

constexpr int N     = 8192;
constexpr int K     = 32;
constexpr int NBINS = 2048;      // positive fp32: bits>>20 in [0, 2048)
constexpr int SPEC_BASE = 1024;  // bin(2.0) = 1024; values > 2.0 -> [1024,2048)
constexpr int CAP   = 512;       // candidate list capacity (expected ~186)
constexpr int SLOTS = CAP / 64;
constexpr int BB    = 128;       // compacted cutoff-bin entries (expected ~26)
constexpr int BLOCK = 256;
constexpr float TSPEC = 2.0f;

typedef float f4 __attribute__((ext_vector_type(4)));

// Find cutoff bin B (the bin containing the K-th largest) and G = count
// strictly above B, from hist[base .. base+64*PER). All waves redundant.
template<int PER>
__device__ __forceinline__ bool find_cutoff(const unsigned* hist, int lane,
                                            int base, int& B, int& G) {
    unsigned s = 0;
    #pragma unroll
    for (int i = 0; i < PER; ++i)
        s += hist[base + lane * PER + ((i + lane) & (PER - 1))];  // staggered
    unsigned acc = s;                       // inclusive suffix sum over lanes
    #pragma unroll
    for (int off = 1; off < 64; off <<= 1) {
        unsigned t = __shfl_down(acc, off, 64);
        if (lane + off < 64) acc += t;
    }
    unsigned long long m = __ballot(acc >= (unsigned)K);
    if (m == 0ull) return false;
    int g = 63 - __clzll((long long)m);     // highest group with suffix >= K
    unsigned above = (g < 63) ? (unsigned)__shfl((int)acc, g + 1, 64) : 0u;
    unsigned h  = (lane < PER) ? hist[base + g * PER + lane] : 0u;
    unsigned a2 = h;                        // within-group suffix
    #pragma unroll
    for (int off = 1; off < 64; off <<= 1) {
        unsigned t = __shfl_down(a2, off, 64);
        if (lane + off < 64) a2 += t;
    }
    unsigned long long m2 = __ballot(above + a2 >= (unsigned)K);
    int bl = 63 - __clzll((long long)m2);
    B = base + g * PER + bl;
    G = (int)(above + (unsigned)__shfl((int)a2, bl, 64)
                    - (unsigned)__shfl((int)h,  bl, 64));
    return true;
}

__global__ __launch_bounds__(BLOCK)
void topk_relu_kernel(const float* __restrict__ A, float* __restrict__ Out) {
    const int row  = blockIdx.x;
    const int tid  = threadIdx.x;
    const int lane = tid & 63;
    const int wave = tid >> 6;

    __shared__ unsigned hist[NBINS];
    __shared__ float    cv[CAP];
    __shared__ int      cc[CAP];
    __shared__ float    bbv[BB];
    __shared__ int      bbc[BB];
    __shared__ unsigned ccnt;

    // zero only the speculative bins [1024, 2048)
    #pragma unroll
    for (int i = 0; i < (NBINS - SPEC_BASE) / BLOCK; ++i)
        hist[SPEC_BASE + tid + i * BLOCK] = 0u;
    if (tid == 0) ccnt = 0u;
    __syncthreads();

    // ---- touch 1 (the ONLY global read of A on the fast path) ----
    const f4* __restrict__ Arow = reinterpret_cast<const f4*>(A + (size_t)row * N);
    #pragma unroll
    for (int i = 0; i < 8; ++i) {
        f4 v = Arow[i * BLOCK + tid];
        #pragma unroll
        for (int c = 0; c < 4; ++c) {
            float f = v[c];
            if (f > TSPEC) {
                atomicAdd(&hist[__float_as_uint(f) >> 20], 1u);
                unsigned ix = atomicAdd(&ccnt, 1u);
                if (ix < CAP) { cv[ix] = f; cc[ix] = (i * BLOCK + tid) * 4 + c; }
            }
        }
    }
    __syncthreads();

    int B, G;
    bool ok = find_cutoff<16>(hist, lane, SPEC_BASE, B, G);
    const unsigned Call = ccnt;             // block-uniform
    f4* __restrict__ Orow4 = reinterpret_cast<f4*>(Out + (size_t)row * N);

    if (ok && Call <= (unsigned)CAP) {
        // ---- fast path: zero burst NOW; its drain overlaps the ranking ----
        const f4 z = {0.0f, 0.0f, 0.0f, 0.0f};
        #pragma unroll
        for (int i = 0; i < 8; ++i)
            __builtin_nontemporal_store(z, Orow4 + i * BLOCK + tid);

        // rank-R boundary (vR, cR) of cutoff bin B (all waves redundant)
        const int R = K - G;
        const int C = (int)Call;
        // ballot-compact bin-B entries into bbv/bbc: every wave writes the
        // SAME values to the same slots (duplicate-identical, no barrier).
        int total = 0;
        #pragma unroll
        for (int s = 0; s < SLOTS; ++s) {
            const int j = lane + s * 64;
            bool flag = false; float fv = 0.0f; int fc = 0;
            if (j < C) {
                fv = cv[j];
                if ((int)(__float_as_uint(fv) >> 20) == B) { flag = true; fc = cc[j]; }
            }
            unsigned long long m = __ballot(flag);
            if (flag) {
                int pos = total + __popcll(m & ((1ull << lane) - 1ull));
                if (pos < BB) { bbv[pos] = fv; bbc[pos] = fc; }
            }
            total += (int)__popcll(m);
        }
        const int T = min(total, BB);       // expected ~26; >= R
        float mv0 = -1.0f, mv1 = -1.0f; int mc0 = 0x7fffffff, mc1 = 0x7fffffff;
        if (lane      < T) { mv0 = bbv[lane];      mc0 = bbc[lane]; }
        if (lane + 64 < T) { mv1 = bbv[lane + 64]; mc1 = bbc[lane + 64]; }
        int r0 = 0, r1 = 0;
        for (int j = 0; j < T; ++j) {       // LDS broadcast reads
            const float vj = bbv[j];
            const int   cj = bbc[j];
            if (vj > mv0 || (vj == mv0 && cj < mc0)) r0++;
            if (vj > mv1 || (vj == mv1 && cj < mc1)) r1++;
        }
        float bv = 0.0f; int bc = -1; bool found = false;
        if (lane      < T && r0 == R - 1) { bv = mv0; bc = mc0; found = true; }
        if (lane + 64 < T && r1 == R - 1) { bv = mv1; bc = mc1; found = true; }
        float vR = __int_as_float(0x7f800000);
        int   cR = -1;
        unsigned long long bm = __ballot(found);
        if (bm != 0ull) {
            int src = (int)__ffsll((long long)bm) - 1;
            vR = __shfl(bv, src, 64);
            cR = __shfl(bc, src, 64);
        }

        __syncthreads();   // drains vmem: zero burst complete before scatter

        if (wave == 0) {
            float* __restrict__ Orow = Out + (size_t)row * N;
            #pragma unroll
            for (int s = 0; s < SLOTS; ++s) {
                const int j = lane + s * 64;
                if (j < C) {
                    float f = cv[j]; int c = cc[j];
                    if (f > vR || (f == vR && c <= cR)) Orow[c] = f;
                }
            }
        }
        return;
    }

    // ---- exact fallback (block-uniform; ~never for N(0,1) rows) ----
    __syncthreads();                        // scan reads done before re-zero
    #pragma unroll
    for (int i = 0; i < NBINS / BLOCK; ++i) hist[tid + i * BLOCK] = 0u;
    if (tid == 0) ccnt = 0u;
    __syncthreads();
    #pragma unroll
    for (int i = 0; i < 8; ++i) {
        f4 v = Arow[i * BLOCK + tid];
        #pragma unroll
        for (int c = 0; c < 4; ++c) {
            float f = v[c];
            if (f > 0.0f) atomicAdd(&hist[__float_as_uint(f) >> 20], 1u);
        }
    }
    __syncthreads();
    if (!find_cutoff<32>(hist, lane, 0, B, G)) { B = -1; G = 0; }
    if (B >= 0) {
        #pragma unroll
        for (int i = 0; i < 8; ++i) {
            f4 v = Arow[i * BLOCK + tid];
            #pragma unroll
            for (int c = 0; c < 4; ++c) {
                float f = v[c];
                if (f > 0.0f && (int)(__float_as_uint(f) >> 20) == B) {
                    unsigned ix = atomicAdd(&ccnt, 1u);
                    if (ix < CAP) { cv[ix] = f; cc[ix] = (i * BLOCK + tid) * 4 + c; }
                }
            }
        }
    }
    __syncthreads();

    float vR = 0.0f;                        // B == -1: keep all positives
    int   cR = -1;
    if (B >= 0) {
        const int R = K - G;
        const int C = (int)min(ccnt, (unsigned)CAP);
        float mv[SLOTS]; int mc[SLOTS]; int rk[SLOTS];
        #pragma unroll
        for (int s = 0; s < SLOTS; ++s) {
            const int j = lane + s * 64;
            if (j < C) { mv[s] = cv[j]; mc[s] = cc[j]; }
            else       { mv[s] = -1.0f; mc[s] = 0x7fffffff; }
            rk[s] = 0;
        }
        for (int j = 0; j < C; ++j) {
            const float vj = cv[j];
            const int   cj = cc[j];
            #pragma unroll
            for (int s = 0; s < SLOTS; ++s)
                if (vj > mv[s] || (vj == mv[s] && cj < mc[s])) rk[s]++;
        }
        float bv = 0.0f; int bc = -1; bool found = false;
        #pragma unroll
        for (int s = 0; s < SLOTS; ++s)
            if (lane + s * 64 < C && rk[s] == R - 1) { bv = mv[s]; bc = mc[s]; found = true; }
        vR = __int_as_float(0x7f800000);
        unsigned long long bm = __ballot(found);
        if (bm != 0ull) {
            int src = (int)__ffsll((long long)bm) - 1;
            vR = __shfl(bv, src, 64);
            cR = __shfl(bc, src, 64);
        }
    }

    // dense emit (fallback only): re-read row (L2-hot) and write everything
    #pragma unroll
    for (int i = 0; i < 8; ++i) {
        f4 v = Arow[i * BLOCK + tid];
        f4 w;
        #pragma unroll
        for (int c = 0; c < 4; ++c) {
            float f   = v[c];
            int   col = (i * BLOCK + tid) * 4 + c;
            w[c] = ((f > vR) || (f == vR && col <= cR)) ? f : 0.0f;
        }
        __builtin_nontemporal_store(w, Orow4 + i * BLOCK + tid);
    }
}

extern "C" void kernel_launch(void* const* d_in, const int* in_sizes, int n_in,
                              void* d_out, int out_size, void* d_ws, size_t ws_size,
                              hipStream_t stream) {
    const float* A   = (const float*)d_in[0];
    float*       Out = (float*)d_out;
    (void)in_sizes; (void)n_in; (void)d_ws; (void)ws_size; (void)out_size;
    topk_relu_kernel<<<dim3(N), dim3(BLOCK), 0, stream>>>(A, Out);
}